// Round 3
// baseline (171.377 us; speedup 1.0000x reference)
//
#include <hip/hip_runtime.h>
#include <hip/hip_fp16.h>
#include <cstdint>
#include <cstddef>

#define Bb 32
#define Ss 2048
#define Ee 1024
#define Qq 1024
#define Aa 512

typedef _Float16 half8 __attribute__((ext_vector_type(8)));
typedef float f32x4 __attribute__((ext_vector_type(4)));

// ---- workspace byte offsets ----
#define WS_PROJQ 0u        // 32*512 f32   = 65536 B
#define WS_MPART 65536u    // 32*16 f32    = 2048 B
#define WS_LPART 67584u    // 32*16 f32    = 2048 B
#define WS_CTXP  69632u    // 32*16*512 f32= 1048576 B
#define WS_WWS   1118208u  // 1024*512 f16 = 1048576 B

__device__ __forceinline__ float fast_tanh(float x) {
  float e = __expf(2.0f * x);
  return 1.0f - __fdividef(2.0f, e + 1.0f);
}

// ---- W_in fp32 [E][A] -> fp16 tiled [kt][kslot][a][8]  (1 MB, contiguous 32KB per kt)
__global__ void k_convw(const float* __restrict__ win, _Float16* __restrict__ wws) {
  int gid = blockIdx.x * 256 + threadIdx.x;
  int a  = gid & 511;
  int ks = (gid >> 9) & 3;
  int kt = gid >> 11;
  int k0 = kt * 32 + ks * 8;
  half8 v;
  #pragma unroll
  for (int j = 0; j < 8; ++j) v[j] = (_Float16)win[(size_t)(k0 + j) * Aa + a];
  *(half8*)(wws + ((size_t)kt * 16384 + (size_t)ks * 4096 + (size_t)a * 8)) = v;
}

// ---- proj_q[b][a]
__global__ void k_projq(const float* __restrict__ query, const float* __restrict__ wq,
                        float* __restrict__ projq) {
  __shared__ float red[256];
  int b  = blockIdx.y;
  int al = threadIdx.x & 63;
  int eq = threadIdx.x >> 6;
  int a  = blockIdx.x * 64 + al;
  const float* q = query + (size_t)b * Qq;
  float s = 0.f;
  int e0 = eq * 256;
  #pragma unroll 4
  for (int e = e0; e < e0 + 256; ++e)
    s += q[e] * wq[(size_t)e * Aa + a];
  red[threadIdx.x] = s;
  __syncthreads();
  if (eq == 0)
    projq[(size_t)b * Aa + a] = red[al] + red[al + 64] + red[al + 128] + red[al + 192];
}

// ---- main kernel: T14 pipelined (issue loads kt+1 -> MFMA kt -> write kt+1 -> barrier)
__global__ __launch_bounds__(512, 2)
void k_main(const float* __restrict__ inp, const _Float16* __restrict__ wws,
            const float* __restrict__ projq, const float* __restrict__ watt,
            float* __restrict__ mpart, float* __restrict__ lpart,
            float* __restrict__ ctxp)
{
  __shared__ __align__(16) _Float16 Alds[2][4 * 128 * 8];  // [p][ks][row][8]  16 KB
  __shared__ __align__(16) _Float16 Blds[2][4 * 512 * 8];  // [p][ks][a][8]    64 KB
  __shared__ float pq_s[512];
  __shared__ float wa_s[512];
  __shared__ float sc4[128][4];
  __shared__ float pbuf[128];
  __shared__ float redv[8];
  __shared__ float ctx2[2][512];

  const int tid = threadIdx.x;
  const int l   = tid & 63;
  const int w   = tid >> 6;
  const int lr  = l & 15;
  const int kb  = l >> 4;
  const int wr  = w >> 2;
  const int wc  = w & 3;
  const int b   = blockIdx.y;
  const int ch  = blockIdx.x;

  pq_s[tid] = projq[(size_t)b * Aa + tid];
  wa_s[tid] = watt[tid];

  // A staging: thread owns (row = w*16+lr, kslot = kb): 8 fp32 per K-step
  const int arow = w * 16 + lr;
  const float* arow_ptr = inp + ((size_t)(b * Ss + ch * 128 + arow)) * Ee + kb * 8;
  const int aoff = (kb * 128 + arow) * 8;      // half8-element offset /8

  // B staging: linear copy, thread copies 4x16B per K-step
  const char* bbase = (const char*)wws + (size_t)tid * 16;
  const int boff = tid * 16;                   // byte offset within Blds[p]

  f32x4 acc[4][8];
  #pragma unroll
  for (int m = 0; m < 4; ++m)
    #pragma unroll
    for (int n = 0; n < 8; ++n) acc[m][n] = (f32x4){0.f, 0.f, 0.f, 0.f};

  // ---- prologue: stage kt=0 into buffer 0
  {
    float4 f0 = *(const float4*)(arow_ptr);
    float4 f1 = *(const float4*)(arow_ptr + 4);
    float4 g0 = *(const float4*)(bbase);
    float4 g1 = *(const float4*)(bbase + 8192);
    float4 g2 = *(const float4*)(bbase + 16384);
    float4 g3 = *(const float4*)(bbase + 24576);
    half8 h;
    h[0]=(_Float16)f0.x; h[1]=(_Float16)f0.y; h[2]=(_Float16)f0.z; h[3]=(_Float16)f0.w;
    h[4]=(_Float16)f1.x; h[5]=(_Float16)f1.y; h[6]=(_Float16)f1.z; h[7]=(_Float16)f1.w;
    *(half8*)(Alds[0] + aoff) = h;
    char* bd = (char*)Blds[0] + boff;
    *(float4*)(bd)         = g0;
    *(float4*)(bd + 8192)  = g1;
    *(float4*)(bd + 16384) = g2;
    *(float4*)(bd + 24576) = g3;
  }
  __syncthreads();

  int p = 0;
  for (int kt = 0; kt < 32; ++kt) {
    // 1) issue next-step global loads FIRST (latency hides under MFMAs)
    const int ktn = (kt < 31) ? kt + 1 : 31;
    const float* ap = arow_ptr + (size_t)ktn * 32;
    float4 f0 = *(const float4*)(ap);
    float4 f1 = *(const float4*)(ap + 4);
    const char* bs = bbase + (size_t)ktn * 32768;
    float4 g0 = *(const float4*)(bs);
    float4 g1 = *(const float4*)(bs + 8192);
    float4 g2 = *(const float4*)(bs + 16384);
    float4 g3 = *(const float4*)(bs + 24576);

    // 2) fragments from LDS[p]
    half8 af[4], bf[8];
    #pragma unroll
    for (int m = 0; m < 4; ++m)
      af[m] = *(const half8*)(Alds[p] + (kb * 128 + wr * 64 + m * 16 + lr) * 8);
    #pragma unroll
    for (int n = 0; n < 8; ++n)
      bf[n] = *(const half8*)(Blds[p] + (kb * 512 + wc * 128 + n * 16 + lr) * 8);

    // 3) MFMA
    #pragma unroll
    for (int m = 0; m < 4; ++m)
      #pragma unroll
      for (int n = 0; n < 8; ++n)
        acc[m][n] = __builtin_amdgcn_mfma_f32_16x16x32_f16(af[m], bf[n], acc[m][n], 0, 0, 0);

    // 4) write kt+1 into LDS[p^1]
    if (kt < 31) {
      half8 h;
      h[0]=(_Float16)f0.x; h[1]=(_Float16)f0.y; h[2]=(_Float16)f0.z; h[3]=(_Float16)f0.w;
      h[4]=(_Float16)f1.x; h[5]=(_Float16)f1.y; h[6]=(_Float16)f1.z; h[7]=(_Float16)f1.w;
      *(half8*)(Alds[p ^ 1] + aoff) = h;
      char* bd = (char*)Blds[p ^ 1] + boff;
      *(float4*)(bd)         = g0;
      *(float4*)(bd + 8192)  = g1;
      *(float4*)(bd + 16384) = g2;
      *(float4*)(bd + 24576) = g3;
    }
    __syncthreads();
    p ^= 1;
  }

  // ---------------- epilogue (unchanged, numerically verified) ----------------
  float sp[4][4];
  #pragma unroll
  for (int m = 0; m < 4; ++m)
    #pragma unroll
    for (int j = 0; j < 4; ++j) sp[m][j] = 0.f;

  #pragma unroll
  for (int n = 0; n < 8; ++n) {
    int col = wc * 128 + n * 16 + lr;
    float wan = wa_s[col], pqn = pq_s[col];
    #pragma unroll
    for (int m = 0; m < 4; ++m)
      #pragma unroll
      for (int j = 0; j < 4; ++j)
        sp[m][j] += fast_tanh(acc[m][n][j] + pqn) * wan;
  }
  #pragma unroll
  for (int m = 0; m < 4; ++m)
    #pragma unroll
    for (int j = 0; j < 4; ++j) {
      float v = sp[m][j];
      v += __shfl_xor(v, 1);
      v += __shfl_xor(v, 2);
      v += __shfl_xor(v, 4);
      v += __shfl_xor(v, 8);
      sp[m][j] = v;
    }
  if (lr == 0) {
    #pragma unroll
    for (int m = 0; m < 4; ++m)
      #pragma unroll
      for (int j = 0; j < 4; ++j)
        sc4[wr * 64 + m * 16 + kb * 4 + j][wc] = sp[m][j];
  }
  __syncthreads();

  if (tid < 128) {
    float s = sc4[tid][0] + sc4[tid][1] + sc4[tid][2] + sc4[tid][3];
    pbuf[tid] = s;
    float mx = s;
    #pragma unroll
    for (int off = 1; off < 64; off <<= 1) mx = fmaxf(mx, __shfl_xor(mx, off));
    if (l == 0) redv[w] = mx;
  }
  __syncthreads();
  float Mx = fmaxf(redv[0], redv[1]);
  if (tid < 128) {
    float pe = __expf(pbuf[tid] - Mx);
    pbuf[tid] = pe;
    float ls = pe;
    #pragma unroll
    for (int off = 1; off < 64; off <<= 1) ls += __shfl_xor(ls, off);
    if (l == 0) redv[4 + w] = ls;
  }
  __syncthreads();

  float cv[8];
  #pragma unroll
  for (int n = 0; n < 8; ++n) cv[n] = 0.f;
  #pragma unroll
  for (int m = 0; m < 4; ++m)
    #pragma unroll
    for (int j = 0; j < 4; ++j) {
      float pw = pbuf[wr * 64 + m * 16 + kb * 4 + j];
      #pragma unroll
      for (int n = 0; n < 8; ++n) cv[n] += pw * acc[m][n][j];
    }
  #pragma unroll
  for (int n = 0; n < 8; ++n) {
    float v = cv[n];
    v += __shfl_xor(v, 16);
    v += __shfl_xor(v, 32);
    cv[n] = v;
  }
  if (l < 16) {
    #pragma unroll
    for (int n = 0; n < 8; ++n) ctx2[wr][wc * 128 + n * 16 + lr] = cv[n];
  }
  __syncthreads();

  int pi = b * 16 + ch;
  ctxp[(size_t)pi * 512 + tid] = ctx2[0][tid] + ctx2[1][tid];
  if (tid == 0) { mpart[pi] = Mx; lpart[pi] = redv[4] + redv[5]; }
}

// ---- merge chunk partials
__global__ void k_comb(const float* __restrict__ mpart, const float* __restrict__ lpart,
                       const float* __restrict__ ctxp, float* __restrict__ out) {
  int b = blockIdx.x, a = threadIdx.x;
  float Mg = -1e30f;
  #pragma unroll
  for (int i = 0; i < 16; ++i) Mg = fmaxf(Mg, mpart[b * 16 + i]);
  float den = 0.f, s = 0.f;
  #pragma unroll
  for (int i = 0; i < 16; ++i) {
    float e = __expf(mpart[b * 16 + i] - Mg);
    den += lpart[b * 16 + i] * e;
    s   += ctxp[((size_t)(b * 16 + i)) * 512 + a] * e;
  }
  out[(size_t)b * 512 + a] = s / den;
}

extern "C" void kernel_launch(void* const* d_in, const int* in_sizes, int n_in,
                              void* d_out, int out_size, void* d_ws, size_t ws_size,
                              hipStream_t stream) {
  const float* inputs = (const float*)d_in[0];
  const float* query  = (const float*)d_in[1];
  const float* W_in   = (const float*)d_in[2];
  const float* W_q    = (const float*)d_in[3];
  const float* w_att  = (const float*)d_in[4];
  float* out = (float*)d_out;

  char* ws = (char*)d_ws;
  float*    projq = (float*)(ws + WS_PROJQ);
  float*    mpart = (float*)(ws + WS_MPART);
  float*    lpart = (float*)(ws + WS_LPART);
  float*    ctxp  = (float*)(ws + WS_CTXP);
  _Float16* wws   = (_Float16*)(ws + WS_WWS);

  k_convw<<<256, 256, 0, stream>>>(W_in, wws);
  k_projq<<<dim3(8, 32), 256, 0, stream>>>(query, W_q, projq);
  k_main<<<dim3(16, 32), 512, 0, stream>>>(inputs, wws, projq, w_att, mpart, lpart, ctxp);
  k_comb<<<32, 512, 0, stream>>>(mpart, lpart, ctxp, out);
}